// Round 8
// baseline (710.389 us; speedup 1.0000x reference)
//
#include <hip/hip_runtime.h>
#include <stdint.h>

typedef unsigned short u16;
typedef __attribute__((ext_vector_type(8))) __bf16 bf16x8;
typedef __attribute__((ext_vector_type(4))) float f32x4;

__device__ __forceinline__ u16 f2bf(float f) {
    union { float f; uint32_t u; } v; v.f = f;
    uint32_t r = (v.u + 0x7FFFu + ((v.u >> 16) & 1u)) >> 16;
    return (u16)r;
}

// Wave-local LDS drain (WAR protection when a window is rewritten).
__device__ __forceinline__ void lds_fence() {
    __asm__ volatile("s_waitcnt lgkmcnt(0)" ::: "memory");
}

#define BM 128
#define BN 128
#define BK 64

// ---------------------------------------------------------------------------
// ROUND 8: fused persistent kernel, NO cooperative API (R7's zero output ==
// hipLaunchCooperativeKernel rejected under graph capture; logic re-audit
// found no numeric bug). Plain <<<1024,256>>> launch; 4 blocks/CU residency
// by construction (LDS 36880B -> 4/CU, VGPR ~60 = the proven R0 resources).
// Grid barrier: device-scope atomic arrival (RELEASE: flushes XCD L2) +
// relaxed spin + ACQUIRE agent fence (invalidates L2) on exit; bounded spin
// so a residency failure yields a wrong answer, not a hang. Counter region
// zeroed per replay via captured hipMemsetAsync.
// Work distribution: per-XCD work-stealing counters per phase — preserves
// the R0 XCD<->tile locality map (tile = xcd + 8*i) AND restores the dynamic
// tail balancing the free-running launcher had in phase 1 (1536 tiles).
// Tile bodies = byte-equivalent R0 baseline (best measured, rounds 1-6).
// lsum atomics -> psum[4z][32][2048] plain partial stores; MODE 3 reduces 32
// partials/row into the spare 512B of wave-0's epilogue window (LDS stays
// 36864 + 16B for the steal index).
// ---------------------------------------------------------------------------

__device__ __forceinline__ void grid_bar(uint* cnt, uint target, int t) {
    __syncthreads();   // all waves done; compiler drains vmcnt before s_barrier
    if (t == 0) {
        __hip_atomic_fetch_add(cnt, 1u, __ATOMIC_RELEASE, __HIP_MEMORY_SCOPE_AGENT);
        uint g = 0;
        while (__hip_atomic_load(cnt, __ATOMIC_RELAXED, __HIP_MEMORY_SCOPE_AGENT) < target) {
            __builtin_amdgcn_s_sleep(2);
            if (++g > (1u << 22)) break;   // ~1s escape: wrong-answer, not hang
        }
        __builtin_amdgcn_fence(__ATOMIC_ACQUIRE, "agent");
    }
    __syncthreads();
}

template<int MODE>
__device__ __forceinline__ void tile_body(
    int id, u16* smem,
    const u16* __restrict__ A, const u16* __restrict__ Bt,
    const float* __restrict__ b0, const float* __restrict__ b1, const float* __restrict__ b2,
    u16* __restrict__ o0, u16* __restrict__ o1, u16* __restrict__ o2,
    float* __restrict__ o3, float* __restrict__ psum,
    int N, int K, long sA, long sB, long sC, float scale)
{
    const int t = threadIdx.x;
    const int lane = t & 63;
    const int wave = t >> 6;
    const int wm = (wave & 1) * 64;
    const int wn = (wave >> 1) * 64;

    // ---- XCD-aware tile decode (id & 7 = XCD of the owning block) ----
    const int xcd = id & 7;
    const int s = id >> 3;
    int bm, bn;
    long bz;
    if (MODE == 0) {        // 1536 tiles: 24 bn x 64 bm; XCD k -> bm band [8k, 8k+8)
        bn = (s >> 3) * BN;
        bm = (xcd * 8 + (s & 7)) * BM;
        bz = 0;
    } else if (MODE == 2) { // 1024 tiles: 16 bn x 16 bm x 4 z
        bz = xcd >> 1;
        bn = (s & 15) * BN;
        bm = ((xcd & 1) * 8 + (s >> 4)) * BM;
    } else {                // 512 tiles: 8 bn x 16 bm x 4 z
        bz = xcd >> 1;
        bn = (s & 7) * BN;
        bm = ((xcd & 1) * 8 + (s >> 3)) * BM;
    }

    const u16* Ab = A + bz * sA;
    const u16* Bb = Bt + bz * sB;

    f32x4 acc[4][4];
#pragma unroll
    for (int i = 0; i < 4; ++i)
#pragma unroll
        for (int j = 0; j < 4; ++j)
            acc[i][j] = (f32x4){0.f, 0.f, 0.f, 0.f};

    const int lrow = t >> 2;          // 0..63
    const int lcol = (t & 3) * 8;     // 0,8,16,24 within a 32-col half
    const int fm = lane & 15;
    const int fk = (lane >> 4) * 8;

    for (int k0 = 0; k0 < K; k0 += BK) {
#pragma unroll
        for (int h = 0; h < 2; ++h)
#pragma unroll
            for (int r = 0; r < 2; ++r) {
                const u16* ga = Ab + (long)(bm + r * 64 + lrow) * K + (k0 + h * 32 + lcol);
                __builtin_amdgcn_global_load_lds(
                    (const __attribute__((address_space(1))) void*)ga,
                    (__attribute__((address_space(3))) void*)&smem[h * 4096 + (r * 256 + t) * 8],
                    16, 0, 0);
            }
#pragma unroll
        for (int h = 0; h < 2; ++h)
#pragma unroll
            for (int r = 0; r < 2; ++r) {
                const u16* gb = Bb + (long)(bn + r * 64 + lrow) * K + (k0 + h * 32 + lcol);
                __builtin_amdgcn_global_load_lds(
                    (const __attribute__((address_space(1))) void*)gb,
                    (__attribute__((address_space(3))) void*)&smem[8192 + h * 4096 + (r * 256 + t) * 8],
                    16, 0, 0);
            }
        __syncthreads();

#pragma unroll
        for (int h = 0; h < 2; ++h) {
            bf16x8 af[4], bfr[4];
#pragma unroll
            for (int i = 0; i < 4; ++i) {
                af[i]  = *(const bf16x8*)&smem[h * 4096 + (wm + i * 16 + fm) * 32 + fk];
                bfr[i] = *(const bf16x8*)&smem[8192 + h * 4096 + (wn + i * 16 + fm) * 32 + fk];
            }
#pragma unroll
            for (int i = 0; i < 4; ++i)
#pragma unroll
                for (int j = 0; j < 4; ++j)
                    acc[i][j] = __builtin_amdgcn_mfma_f32_16x16x32_bf16(af[i], bfr[j], acc[i][j], 0, 0, 0);
        }
        __syncthreads();
    }

    // C/D layout: col = lane&15, row = (lane>>4)*4 + reg
    const int cm = (lane >> 4) * 4;
    const int cn = lane & 15;
    u16* Ew = smem + wave * 4608; // 9216 B per-wave window

    if (MODE == 3) {
        // ---- denominator: 32 psum partials/row -> spare 512B of wave-0 window
        float* denom = (float*)((char*)smem + 8704);  // bytes 8704..9215, untouched by Fw
        if (t < 128) {
            float d = 0.f;
#pragma unroll
            for (int j = 0; j < 32; ++j)
                d += psum[(bz * 32 + j) * 2048 + bm + t];
            denom[t] = d;
        }
        __syncthreads();
        // ---- fp32 out (PV), /denom[row]: 2 passes of 32 rows, stride 68 ----
        float* Fw = (float*)Ew; // 32*68*4 = 8704 B <= 9216
#pragma unroll
        for (int p = 0; p < 2; ++p) {
            if (p) lds_fence();
#pragma unroll
            for (int ii = 0; ii < 2; ++ii) {
                const int i = p * 2 + ii;
#pragma unroll
                for (int j = 0; j < 4; ++j)
#pragma unroll
                    for (int r = 0; r < 4; ++r)
                        Fw[(ii * 16 + cm + r) * 68 + j * 16 + cn] = acc[i][j][r];
            }
#pragma unroll
            for (int it = 0; it < 8; ++it) {
                const int row = it * 4 + (lane >> 4);
                const int c4 = (lane & 15) * 4;
                f32x4 w = *(const f32x4*)&Fw[row * 68 + c4];
                const int lr = wm + p * 32 + row;
                const float inv = __builtin_amdgcn_rcpf(denom[lr]);
                w[0] *= inv; w[1] *= inv; w[2] *= inv; w[3] *= inv;
                *(f32x4*)&o3[bz * sC + (long)(bm + lr) * N + bn + wn + c4] = w;
            }
        }
    } else if (MODE == 0 && (bn >> 10) == 2) {
        // ---- v projection: transposed [b,e,s]; single-shot ----
        float bb[4];
#pragma unroll
        for (int j = 0; j < 4; ++j) bb[j] = b2[(bn & 1023) + wn + j * 16 + cn];
        const int bgi = (bm + wm) >> 11;
        const int sbase = (bm + wm) & 2047;
#pragma unroll
        for (int i = 0; i < 4; ++i)
#pragma unroll
            for (int j = 0; j < 4; ++j) {
                ushort4 pk;
                pk.x = f2bf(acc[i][j][0] + bb[j]);
                pk.y = f2bf(acc[i][j][1] + bb[j]);
                pk.z = f2bf(acc[i][j][2] + bb[j]);
                pk.w = f2bf(acc[i][j][3] + bb[j]);
                *(ushort4*)&Ew[(j * 16 + cn) * 72 + i * 16 + cm] = pk; // [e][s]
            }
#pragma unroll
        for (int it = 0; it < 8; ++it) {
            const int e = it * 8 + (lane >> 3);
            const int s8 = (lane & 7) * 8;
            const uint4 w = *(const uint4*)&Ew[e * 72 + s8];
            const int eg = (bn & 1023) + wn + e;
            *(uint4*)&o2[((((long)bgi << 10) + eg) << 11) + sbase + s8] = w;
        }
    } else if (MODE == 0) {
        // ---- q/k projection, row-major bf16, single-shot ----
        const int sec = bn >> 10;
        u16* C = sec ? o1 : o0;
        const float* bias = sec ? b1 : b0;
        const int ncol0 = bn & 1023;
        float bb[4];
#pragma unroll
        for (int j = 0; j < 4; ++j) bb[j] = bias[ncol0 + wn + j * 16 + cn];
#pragma unroll
        for (int i = 0; i < 4; ++i)
#pragma unroll
            for (int j = 0; j < 4; ++j) {
                const int col = j * 16 + cn;
#pragma unroll
                for (int r = 0; r < 4; ++r)
                    Ew[(i * 16 + cm + r) * 72 + col] = f2bf(acc[i][j][r] + bb[j]);
            }
#pragma unroll
        for (int it = 0; it < 8; ++it) {
            const int row = it * 8 + (lane >> 3);
            const int c8 = (lane & 7) * 8;
            const uint4 w = *(const uint4*)&Ew[row * 72 + c8];
            const int gm = bm + wm + row;
            *(uint4*)&C[(long)gm * 1024 + ncol0 + wn + c8] = w;
        }
    } else {
        // ---- MODE 2: exp(s*scale), psum partial stores, bf16 retile ----
#pragma unroll
        for (int i = 0; i < 4; ++i)
#pragma unroll
            for (int j = 0; j < 4; ++j)
#pragma unroll
                for (int r = 0; r < 4; ++r)
                    acc[i][j][r] = __expf(acc[i][j][r] * scale);
        const int slot = (bn >> 7) * 2 + (wn >> 6);   // bnTile*2 + wnHalf, 0..31
#pragma unroll
        for (int i = 0; i < 4; ++i) {
#pragma unroll
            for (int r = 0; r < 4; ++r) {
                float sm = acc[i][0][r] + acc[i][1][r] + acc[i][2][r] + acc[i][3][r];
                sm += __shfl_xor(sm, 1);
                sm += __shfl_xor(sm, 2);
                sm += __shfl_xor(sm, 4);
                sm += __shfl_xor(sm, 8);
                if (cn == 0)
                    psum[(bz * 32 + slot) * 2048 + bm + wm + i * 16 + cm + r] = sm;
            }
        }
#pragma unroll
        for (int i = 0; i < 4; ++i)
#pragma unroll
            for (int j = 0; j < 4; ++j) {
                const int col = j * 16 + cn;
#pragma unroll
                for (int r = 0; r < 4; ++r)
                    Ew[(i * 16 + cm + r) * 72 + col] = f2bf(acc[i][j][r]);
            }
#pragma unroll
        for (int it = 0; it < 8; ++it) {
            const int row = it * 8 + (lane >> 3);
            const int c8 = (lane & 7) * 8;
            const uint4 w = *(const uint4*)&Ew[row * 72 + c8];
            const int gm = bm + wm + row;
            *(uint4*)&o0[bz * sC + (long)gm * N + bn + wn + c8] = w;
        }
    }
}

__global__ __launch_bounds__(256, 4) void fused_attn(
    const float* __restrict__ x,
    const float* __restrict__ Wq, const float* __restrict__ bq,
    const float* __restrict__ Wk, const float* __restrict__ bk,
    const float* __restrict__ Wv, const float* __restrict__ bv,
    u16* xb, u16* wb, u16* qb, u16* kb, u16* vbT, u16* sb,
    float* psum, float* out, uint* sync)
{
    __shared__ __align__(16) u16 smem[4 * 64 * 72]; // 36864 B
    __shared__ uint widx;                           // steal broadcast

    const int b = blockIdx.x;
    const int t = threadIdx.x;
    const int xcd = b & 7;

    // ---- phase 0: fp32 -> bf16 converts (11264 tiles, 11 per block) ----
#pragma unroll
    for (int j = 0; j < 11; ++j) {
        const int bb = b + (j << 10);
        const float* src; u16* dst; long base;
        if (bb < 8192)       { src = x;  dst = xb;             base = (long)bb << 10; }
        else if (bb < 9216)  { src = Wq; dst = wb;             base = (long)(bb - 8192) << 10; }
        else if (bb < 10240) { src = Wk; dst = wb + (1 << 20); base = (long)(bb - 9216) << 10; }
        else                 { src = Wv; dst = wb + (2 << 20); base = (long)(bb - 10240) << 10; }
        const long i = base + t * 4;
        const f32x4 f = *(const f32x4*)(src + i);
        ushort4 o;
        o.x = f2bf(f[0]); o.y = f2bf(f[1]); o.z = f2bf(f[2]); o.w = f2bf(f[3]);
        *(ushort4*)(dst + i) = o;
    }
    grid_bar(sync, 1024, t);

    // ---- phase 1: fused QKV (1536 tiles; per-XCD steal, pool 192) ----
    for (;;) {
        __syncthreads();           // protect smem vs previous tile's epilogue
        if (t == 0) widx = __hip_atomic_fetch_add(&sync[8 + xcd], 1u,
                             __ATOMIC_RELAXED, __HIP_MEMORY_SCOPE_AGENT);
        __syncthreads();
        const uint i = widx;
        if (i >= 192) break;
        tile_body<0>(xcd + 8 * (int)i, smem, xb, wb, bq, bk, bv, qb, kb, vbT,
                     nullptr, nullptr, 3072, 1024, 0, 0, 0, 1.f);
    }
    grid_bar(sync, 2048, t);

    // ---- phase 2: exp(q.k^T/32) + row partials (1024 tiles; pool 128) ----
    for (;;) {
        __syncthreads();
        if (t == 0) widx = __hip_atomic_fetch_add(&sync[16 + xcd], 1u,
                             __ATOMIC_RELAXED, __HIP_MEMORY_SCOPE_AGENT);
        __syncthreads();
        const uint i = widx;
        if (i >= 128) break;
        tile_body<2>(xcd + 8 * (int)i, smem, qb, kb, nullptr, nullptr, nullptr,
                     sb, nullptr, nullptr, nullptr, psum, 2048, 1024,
                     (long)2048 * 1024, (long)2048 * 1024, (long)2048 * 2048, 0.03125f);
    }
    grid_bar(sync, 3072, t);

    // ---- phase 3: PV / denom (512 tiles; pool 64) ----
    for (;;) {
        __syncthreads();
        if (t == 0) widx = __hip_atomic_fetch_add(&sync[24 + xcd], 1u,
                             __ATOMIC_RELAXED, __HIP_MEMORY_SCOPE_AGENT);
        __syncthreads();
        const uint i = widx;
        if (i >= 64) break;
        tile_body<3>(xcd + 8 * (int)i, smem, sb, vbT, nullptr, nullptr, nullptr,
                     nullptr, nullptr, nullptr, out, psum, 1024, 2048,
                     (long)2048 * 2048, (long)1024 * 2048, (long)2048 * 1024, 1.f);
    }
}

extern "C" void kernel_launch(void* const* d_in, const int* in_sizes, int n_in,
                              void* d_out, int out_size, void* d_ws, size_t ws_size,
                              hipStream_t stream) {
    const float* x  = (const float*)d_in[0];
    const float* Wq = (const float*)d_in[1];
    const float* bq = (const float*)d_in[2];
    const float* Wk = (const float*)d_in[3];
    const float* bk = (const float*)d_in[4];
    const float* Wv = (const float*)d_in[5];
    const float* bv = (const float*)d_in[6];
    float* out = (float*)d_out;

    const int B = 4, S = 2048, D = 1024, E = 1024;
    const int M = B * S; // 8192

    u16* xb  = (u16*)d_ws;                       // [M,D]
    u16* wb  = xb  + (size_t)M * D;              // [3E,D]
    u16* qb  = wb  + (size_t)3 * E * D;          // [M,E]
    u16* kb  = qb  + (size_t)M * E;              // [M,E]
    u16* vbT = kb  + (size_t)M * E;              // [B,E,S]
    u16* sb  = vbT + (size_t)M * E;              // [B,S,S] exp-scores
    float* psum = (float*)(sb + (size_t)M * S);  // [B,32,S] row partials (1 MB)
    uint* sync  = (uint*)(psum + (size_t)4 * 32 * 2048); // [32] barrier+steal ctrs

    hipMemsetAsync(sync, 0, 128, stream);
    fused_attn<<<1024, 256, 0, stream>>>(
        x, Wq, bq, Wk, bk, Wv, bv, xb, wb, qb, kb, vbT, sb, psum, out, sync);
}

// Round 9
// 235.588 us; speedup vs baseline: 3.0154x; 3.0154x over previous
//
#include <hip/hip_runtime.h>
#include <stdint.h>

typedef unsigned short u16;
typedef __attribute__((ext_vector_type(8))) __bf16 bf16x8;
typedef __attribute__((ext_vector_type(4))) float f32x4;

__device__ __forceinline__ u16 f2bf(float f) {
    union { float f; uint32_t u; } v; v.f = f;
    uint32_t r = (v.u + 0x7FFFu + ((v.u >> 16) & 1u)) >> 16;
    return (u16)r;
}

// Wave-local LDS drain (WAR protection when a window is rewritten).
__device__ __forceinline__ void lds_fence() {
    __asm__ volatile("s_waitcnt lgkmcnt(0)" ::: "memory");
}

#define BM 128
#define BN 128
#define BK 64   // staged as two [128][32] halves (round-7 structure, best measured)

// C = A * Bt^T, A [M,K] bf16 rm, Bt [N,K] bf16 rm. K % 64 == 0.
// ROUND 9: byte-for-byte restore of the best measured kernel (R0, 229.7us).
// Session evidence (rounds 1-8): every structural lever on this K=1024 shape
// is null or negative — 8-phase/counted-vmcnt (null), deeper vmcnt (null),
// read-ahead 1-bar phases (null), B-via-global-gather (-2x), fat-wave 1/SIMD
// (-35%), m3 re-tile (null), cooperative fusion (no-launch), persistent
// fusion with device barriers (-3x: ~150us/grid-barrier on MI355X from
// serialized RMW arrival + per-block L2 wb/inv; launch gaps are only ~45us
// total — the stream-ordered launch IS the cheap barrier).
// MODE 0: fused QKV projection, N=3072, grid 1536. Section bn>>10: 0->q(b0,o0),
//         1->k(b1,o1), 2->v(b2) TRANSPOSED [b,e,s] into o2.
// MODE 2: exp(s*scale) bf16 into o0 + atomic row sums into lsum. grid 1024.
// MODE 3: fp32 out = acc / lsum[row] into o3. grid 512.
template<int MODE>
__global__ __launch_bounds__(256, 4) void gemm_bt(
    const u16* __restrict__ A, const u16* __restrict__ Bt,
    const float* __restrict__ b0, const float* __restrict__ b1, const float* __restrict__ b2,
    u16* __restrict__ o0, u16* __restrict__ o1, u16* __restrict__ o2,
    float* __restrict__ o3, float* __restrict__ lsum,
    int M, int N, int K, long sA, long sB, long sC, float scale)
{
    __shared__ __align__(16) u16 smem[4 * 64 * 72]; // 36864 B
    // staging: A half0 @0, A half1 @4096, B half0 @8192, B half1 @12288 (u16 idx)

    const int t = threadIdx.x;
    const int lane = t & 63;
    const int wave = t >> 6;
    const int wm = (wave & 1) * 64;
    const int wn = (wave >> 1) * 64;

    // ---- XCD-aware block swizzle ----
    const int id = blockIdx.x;
    const int xcd = id & 7;
    const int s = id >> 3;
    int bm, bn;
    long bz;
    if (MODE == 0) {        // 1536 blocks: 24 bn x 64 bm; XCD k -> bm band [8k, 8k+8)
        bn = (s >> 3) * BN;
        bm = (xcd * 8 + (s & 7)) * BM;
        bz = 0;
    } else if (MODE == 2) { // 1024 blocks: 16 bn x 16 bm x 4 z; XCD -> (z, bm half)
        bz = xcd >> 1;
        bn = (s & 15) * BN;
        bm = ((xcd & 1) * 8 + (s >> 4)) * BM;
    } else {                // 512 blocks: 8 bn x 16 bm x 4 z; XCD -> (z, bm half)
        bz = xcd >> 1;
        bn = (s & 7) * BN;
        bm = ((xcd & 1) * 8 + (s >> 3)) * BM;
    }

    const u16* Ab = A + bz * sA;
    const u16* Bb = Bt + bz * sB;

    f32x4 acc[4][4];
#pragma unroll
    for (int i = 0; i < 4; ++i)
#pragma unroll
        for (int j = 0; j < 4; ++j)
            acc[i][j] = (f32x4){0.f, 0.f, 0.f, 0.f};

    const int lrow = t >> 2;          // 0..63
    const int lcol = (t & 3) * 8;     // 0,8,16,24 within a 32-col half
    const int fm = lane & 15;
    const int fk = (lane >> 4) * 8;

    for (int k0 = 0; k0 < K; k0 += BK) {
#pragma unroll
        for (int h = 0; h < 2; ++h)
#pragma unroll
            for (int r = 0; r < 2; ++r) {
                const u16* ga = Ab + (long)(bm + r * 64 + lrow) * K + (k0 + h * 32 + lcol);
                __builtin_amdgcn_global_load_lds(
                    (const __attribute__((address_space(1))) void*)ga,
                    (__attribute__((address_space(3))) void*)&smem[h * 4096 + (r * 256 + t) * 8],
                    16, 0, 0);
            }
#pragma unroll
        for (int h = 0; h < 2; ++h)
#pragma unroll
            for (int r = 0; r < 2; ++r) {
                const u16* gb = Bb + (long)(bn + r * 64 + lrow) * K + (k0 + h * 32 + lcol);
                __builtin_amdgcn_global_load_lds(
                    (const __attribute__((address_space(1))) void*)gb,
                    (__attribute__((address_space(3))) void*)&smem[8192 + h * 4096 + (r * 256 + t) * 8],
                    16, 0, 0);
            }
        __syncthreads();

#pragma unroll
        for (int h = 0; h < 2; ++h) {
            bf16x8 af[4], bfr[4];
#pragma unroll
            for (int i = 0; i < 4; ++i) {
                af[i]  = *(const bf16x8*)&smem[h * 4096 + (wm + i * 16 + fm) * 32 + fk];
                bfr[i] = *(const bf16x8*)&smem[8192 + h * 4096 + (wn + i * 16 + fm) * 32 + fk];
            }
#pragma unroll
            for (int i = 0; i < 4; ++i)
#pragma unroll
                for (int j = 0; j < 4; ++j)
                    acc[i][j] = __builtin_amdgcn_mfma_f32_16x16x32_bf16(af[i], bfr[j], acc[i][j], 0, 0, 0);
        }
        __syncthreads();
    }

    // C/D layout: col = lane&15, row = (lane>>4)*4 + reg
    const int cm = (lane >> 4) * 4;
    const int cn = lane & 15;
    u16* Ew = smem + wave * 4608; // 9216 B per-wave window

    if (MODE == 3) {
        // ---- fp32 out (PV), /lsum[row]: 2 passes of 32 rows, stride 68 fp32 ----
        float* Fw = (float*)Ew; // 32*68*4 = 8704 B <= 9216
#pragma unroll
        for (int p = 0; p < 2; ++p) {
            if (p) lds_fence();
#pragma unroll
            for (int ii = 0; ii < 2; ++ii) {
                const int i = p * 2 + ii;
#pragma unroll
                for (int j = 0; j < 4; ++j)
#pragma unroll
                    for (int r = 0; r < 4; ++r)
                        Fw[(ii * 16 + cm + r) * 68 + j * 16 + cn] = acc[i][j][r];
            }
#pragma unroll
            for (int it = 0; it < 8; ++it) {
                const int row = it * 4 + (lane >> 4);
                const int c4 = (lane & 15) * 4;
                f32x4 w = *(const f32x4*)&Fw[row * 68 + c4];
                const int gm = bm + wm + p * 32 + row;
                const float inv = __builtin_amdgcn_rcpf(lsum[bz * 2048 + gm]);
                w[0] *= inv; w[1] *= inv; w[2] *= inv; w[3] *= inv;
                *(f32x4*)&o3[bz * sC + (long)gm * N + bn + wn + c4] = w;
            }
        }
    } else if (MODE == 0 && (bn >> 10) == 2) {
        // ---- v projection: transposed [b,e,s]; single-shot ----
        float bb[4];
#pragma unroll
        for (int j = 0; j < 4; ++j) bb[j] = b2[(bn & 1023) + wn + j * 16 + cn];
        const int bgi = (bm + wm) >> 11;
        const int sbase = (bm + wm) & 2047;
#pragma unroll
        for (int i = 0; i < 4; ++i)
#pragma unroll
            for (int j = 0; j < 4; ++j) {
                ushort4 pk;
                pk.x = f2bf(acc[i][j][0] + bb[j]);
                pk.y = f2bf(acc[i][j][1] + bb[j]);
                pk.z = f2bf(acc[i][j][2] + bb[j]);
                pk.w = f2bf(acc[i][j][3] + bb[j]);
                *(ushort4*)&Ew[(j * 16 + cn) * 72 + i * 16 + cm] = pk; // [e][s]
            }
#pragma unroll
        for (int it = 0; it < 8; ++it) {
            const int e = it * 8 + (lane >> 3);
            const int s8 = (lane & 7) * 8;
            const uint4 w = *(const uint4*)&Ew[e * 72 + s8];
            const int eg = (bn & 1023) + wn + e;
            *(uint4*)&o2[((((long)bgi << 10) + eg) << 11) + sbase + s8] = w;
        }
    } else if (MODE == 0) {
        // ---- q/k projection, row-major bf16, single-shot ----
        const int sec = bn >> 10;
        u16* C = sec ? o1 : o0;
        const float* bias = sec ? b1 : b0;
        const int ncol0 = bn & 1023;
        float bb[4];
#pragma unroll
        for (int j = 0; j < 4; ++j) bb[j] = bias[ncol0 + wn + j * 16 + cn];
#pragma unroll
        for (int i = 0; i < 4; ++i)
#pragma unroll
            for (int j = 0; j < 4; ++j) {
                const int col = j * 16 + cn;
#pragma unroll
                for (int r = 0; r < 4; ++r)
                    Ew[(i * 16 + cm + r) * 72 + col] = f2bf(acc[i][j][r] + bb[j]);
            }
#pragma unroll
        for (int it = 0; it < 8; ++it) {
            const int row = it * 8 + (lane >> 3);
            const int c8 = (lane & 7) * 8;
            const uint4 w = *(const uint4*)&Ew[row * 72 + c8];
            const int gm = bm + wm + row;
            *(uint4*)&C[(long)gm * 1024 + ncol0 + wn + c8] = w;
        }
    } else {
        // ---- MODE 2: exp(s*scale), row-sum atomics, single-shot bf16 retile ----
#pragma unroll
        for (int i = 0; i < 4; ++i)
#pragma unroll
            for (int j = 0; j < 4; ++j)
#pragma unroll
                for (int r = 0; r < 4; ++r)
                    acc[i][j][r] = __expf(acc[i][j][r] * scale);
#pragma unroll
        for (int i = 0; i < 4; ++i) {
#pragma unroll
            for (int r = 0; r < 4; ++r) {
                float sm = acc[i][0][r] + acc[i][1][r] + acc[i][2][r] + acc[i][3][r];
                sm += __shfl_xor(sm, 1);
                sm += __shfl_xor(sm, 2);
                sm += __shfl_xor(sm, 4);
                sm += __shfl_xor(sm, 8);
                if (cn == 0)
                    atomicAdd(&lsum[bz * 2048 + bm + wm + i * 16 + cm + r], sm);
            }
        }
#pragma unroll
        for (int i = 0; i < 4; ++i)
#pragma unroll
            for (int j = 0; j < 4; ++j) {
                const int col = j * 16 + cn;
#pragma unroll
                for (int r = 0; r < 4; ++r)
                    Ew[(i * 16 + cm + r) * 72 + col] = f2bf(acc[i][j][r]);
            }
#pragma unroll
        for (int it = 0; it < 8; ++it) {
            const int row = it * 8 + (lane >> 3);
            const int c8 = (lane & 7) * 8;
            const uint4 w = *(const uint4*)&Ew[row * 72 + c8];
            const int gm = bm + wm + row;
            *(uint4*)&o0[bz * sC + (long)gm * N + bn + wn + c8] = w;
        }
    }
}

// fp32 -> bf16 converts + lsum zeroing.
__global__ __launch_bounds__(256) void cvt_all(
    const float* __restrict__ x, const float* __restrict__ wq,
    const float* __restrict__ wk, const float* __restrict__ wv,
    u16* __restrict__ xb, u16* __restrict__ wb, float* __restrict__ lsum)
{
    const int b = blockIdx.x;
    if (b >= 11264) {
        const long i = (long)(b - 11264) * 1024 + threadIdx.x * 4;
        *(f32x4*)(lsum + i) = (f32x4){0.f, 0.f, 0.f, 0.f};
        return;
    }
    const float* src; u16* dst; long base;
    if (b < 8192)       { src = x;  dst = xb;             base = (long)b * 1024; }
    else if (b < 9216)  { src = wq; dst = wb;             base = (long)(b - 8192) * 1024; }
    else if (b < 10240) { src = wk; dst = wb + (1 << 20); base = (long)(b - 9216) * 1024; }
    else                { src = wv; dst = wb + (2 << 20); base = (long)(b - 10240) * 1024; }
    const long i = base + threadIdx.x * 4;
    const f32x4 f = *(const f32x4*)(src + i);
    ushort4 o;
    o.x = f2bf(f[0]); o.y = f2bf(f[1]); o.z = f2bf(f[2]); o.w = f2bf(f[3]);
    *(ushort4*)(dst + i) = o;
}

extern "C" void kernel_launch(void* const* d_in, const int* in_sizes, int n_in,
                              void* d_out, int out_size, void* d_ws, size_t ws_size,
                              hipStream_t stream) {
    const float* x  = (const float*)d_in[0];
    const float* Wq = (const float*)d_in[1];
    const float* bq = (const float*)d_in[2];
    const float* Wk = (const float*)d_in[3];
    const float* bk = (const float*)d_in[4];
    const float* Wv = (const float*)d_in[5];
    const float* bv = (const float*)d_in[6];
    float* out = (float*)d_out;

    const int B = 4, S = 2048, D = 1024, E = 1024;
    const int M = B * S; // 8192

    u16* xb  = (u16*)d_ws;                       // [M,D]
    u16* wb  = xb  + (size_t)M * D;              // [3E,D]
    u16* qb  = wb  + (size_t)3 * E * D;          // [M,E]
    u16* kb  = qb  + (size_t)M * E;              // [M,E]
    u16* vbT = kb  + (size_t)M * E;              // [B,E,S]
    u16* sb  = vbT + (size_t)M * E;              // [B,S,S] exp-scores
    float* lsum = (float*)(sb + (size_t)M * S);  // [M]

    cvt_all<<<11272, 256, 0, stream>>>(x, Wq, Wk, Wv, xb, wb, lsum);

    dim3 blk(256);
    gemm_bt<0><<<1536, blk, 0, stream>>>(
        xb, wb, bq, bk, bv, qb, kb, vbT, nullptr, nullptr, M, 3 * E, D, 0, 0, 0, 1.f);
    gemm_bt<2><<<1024, blk, 0, stream>>>(
        qb, kb, nullptr, nullptr, nullptr, sb, nullptr, nullptr, nullptr, lsum,
        S, S, E, (long)S * E, (long)S * E, (long)S * S, 0.03125f);
    gemm_bt<3><<<512, blk, 0, stream>>>(
        sb, vbT, nullptr, nullptr, nullptr, nullptr, nullptr, nullptr, out, lsum,
        S, E, S, (long)S * S, (long)E * S, (long)S * E, 1.f);
}